// Round 1
// baseline (533.322 us; speedup 1.0000x reference)
//
#include <hip/hip_runtime.h>
#include <stdint.h>

#define NPTS 2048
#define SOUT 512
#define NB   2
#define TB   256
#define FMAGIC 0xC0DE0000u

typedef float vf2 __attribute__((ext_vector_type(2)));

// ---- DPP wave64 max-reduce (nonneg values; bound_ctrl zero-fill is safe) ----
__device__ __forceinline__ float wave_allmax_f32(float v) {
    int x = __float_as_int(v); int t;
    t = __builtin_amdgcn_update_dpp(x, x, 0x111, 0xF, 0xF, true); v = fmaxf(v, __int_as_float(t)); x = __float_as_int(v);
    t = __builtin_amdgcn_update_dpp(x, x, 0x112, 0xF, 0xF, true); v = fmaxf(v, __int_as_float(t)); x = __float_as_int(v);
    t = __builtin_amdgcn_update_dpp(x, x, 0x114, 0xF, 0xF, true); v = fmaxf(v, __int_as_float(t)); x = __float_as_int(v);
    t = __builtin_amdgcn_update_dpp(x, x, 0x118, 0xF, 0xF, true); v = fmaxf(v, __int_as_float(t)); x = __float_as_int(v);
    t = __builtin_amdgcn_update_dpp(x, x, 0x142, 0xA, 0xF, true); v = fmaxf(v, __int_as_float(t)); x = __float_as_int(v);
    t = __builtin_amdgcn_update_dpp(x, x, 0x143, 0xC, 0xF, true); v = fmaxf(v, __int_as_float(t)); x = __float_as_int(v);
    return __int_as_float(__builtin_amdgcn_readlane(x, 63));
}
__device__ __forceinline__ float lane_bcast(float v, int l) {
    return __int_as_float(__builtin_amdgcn_readlane(__float_as_int(v), l));
}

// =================== FPS role — SINGLE WAVE (no LDS, no barriers) ============
// One wave holds all 2048 points in registers (32 pts/lane, contiguous:
// n = lane*32 + slot). Per round: distance update + in-lane coords-carrying
// argmax tree + DPP wave-reduce + ballot broadcast. Identical arithmetic to
// the proven 4-wave version (fp contract off, rn each op, fminf chain,
// first-occurrence tie-break: >= keeps lower slot, ballot picks lower lane).
// Publisher (FUSED): tri-lane relaxed centroid store each round; release
// flag every 16 rounds BEFORE that round's stores (covers rounds < s; the
// release's wave-wide vmcnt(0) drains all prior lanes' stores).
template<bool FUSED>
__device__ __forceinline__ void fps_role_sw(const float* __restrict__ xb,
                                            float* __restrict__ ob,
                                            unsigned* flagp, int far, int lane) {
    vf2 PX[16], PY[16], PZ[16], DD[16];
    {
        const float4* src = (const float4*)(xb + (size_t)lane * 96);
#pragma unroll
        for (int g = 0; g < 8; ++g) {
            float4 a  = src[g*3+0];
            float4 b4 = src[g*3+1];
            float4 c4 = src[g*3+2];
            // local points 4g..4g+3: (a.x,a.y,a.z) (a.w,b.x,b.y) (b.z,b.w,c.x) (c.y,c.z,c.w)
            PX[2*g+0].x = a.x;  PY[2*g+0].x = a.y;  PZ[2*g+0].x = a.z;
            PX[2*g+0].y = a.w;  PY[2*g+0].y = b4.x; PZ[2*g+0].y = b4.y;
            PX[2*g+1].x = b4.z; PY[2*g+1].x = b4.w; PZ[2*g+1].x = c4.x;
            PX[2*g+1].y = c4.y; PY[2*g+1].y = c4.z; PZ[2*g+1].y = c4.w;
            DD[2*g+0].x = 1e10f; DD[2*g+0].y = 1e10f;
            DD[2*g+1].x = 1e10f; DD[2*g+1].y = 1e10f;
        }
    }
    float cx = xb[far*3+0], cy = xb[far*3+1], cz = xb[far*3+2];

    for (int s = 0; s < SOUT - 1; ++s) {
        if (FUSED) {
            if (lane == 32 && s >= 16 && (s & 15) == 0)   // covers rounds < s
                __hip_atomic_store(flagp, FMAGIC + (unsigned)s,
                                   __ATOMIC_RELEASE, __HIP_MEMORY_SCOPE_AGENT);
            if (lane >= 32 && lane < 35) {                // one vmem, 3 lanes
                float v = (lane == 32) ? cx : ((lane == 33) ? cy : cz);
                unsigned* o = (unsigned*)ob + s * 3 + (lane - 32);
                __hip_atomic_store(o, __float_as_uint(v),
                                   __ATOMIC_RELAXED, __HIP_MEMORY_SCOPE_AGENT);
            }
        } else {
            if (lane == 0) { ob[s*3+0] = cx; ob[s*3+1] = cy; ob[s*3+2] = cz; }
        }
        // --- update all 32 pts + 4 parallel running-argmax chains (8 pts each)
        float bq[4], xq[4], yq[4], zq[4];
        {
#pragma clang fp contract(off)
            vf2 vcx; vcx.x = cx; vcx.y = cx;
            vf2 vcy; vcy.x = cy; vcy.y = cy;
            vf2 vcz; vcz.x = cz; vcz.y = cz;
#pragma unroll
            for (int q = 0; q < 4; ++q) {
#pragma unroll
                for (int jj = 0; jj < 4; ++jj) {
                    const int j = q * 4 + jj;
                    vf2 dx = PX[j] - vcx;
                    vf2 dy = PY[j] - vcy;
                    vf2 dz = PZ[j] - vcz;
                    vf2 d2 = (dx*dx + dy*dy) + dz*dz;   // ((xx+yy)+zz), rn each
                    DD[j].x = fminf(DD[j].x, d2.x);
                    DD[j].y = fminf(DD[j].y, d2.y);
                    // within-vf2: lower slot wins ties (>=)
                    bool l  = DD[j].x >= DD[j].y;
                    float vv = l ? DD[j].x : DD[j].y;
                    float xx = l ? PX[j].x : PX[j].y;
                    float yy = l ? PY[j].x : PY[j].y;
                    float zz = l ? PZ[j].x : PZ[j].y;
                    if (jj == 0) { bq[q] = vv; xq[q] = xx; yq[q] = yy; zq[q] = zz; }
                    else {
                        bool g = bq[q] >= vv;             // earlier slot wins ties
                        bq[q] = g ? bq[q] : vv;
                        xq[q] = g ? xq[q] : xx;
                        yq[q] = g ? yq[q] : yy;
                        zq[q] = g ? zq[q] : zz;
                    }
                }
            }
        }
        // merge 4 chains (ascending index order preserved; >= keeps earlier)
        bool l01 = bq[0] >= bq[1];
        float v01 = l01 ? bq[0] : bq[1];
        float x01 = l01 ? xq[0] : xq[1];
        float y01 = l01 ? yq[0] : yq[1];
        float z01 = l01 ? zq[0] : zq[1];
        bool l23 = bq[2] >= bq[3];
        float v23 = l23 ? bq[2] : bq[3];
        float x23 = l23 ? xq[2] : xq[3];
        float y23 = l23 ? yq[2] : yq[3];
        float z23 = l23 ? zq[2] : zq[3];
        bool lf = v01 >= v23;
        float bv = lf ? v01 : v23;
        float bx = lf ? x01 : x23;
        float by = lf ? y01 : y23;
        float bz = lf ? z01 : z23;
        // wave reduce + first-occurrence lane pick + coord broadcast
        float wmax = wave_allmax_f32(bv);
        unsigned long long msk = __ballot(bv == wmax);
        int l0 = (int)__builtin_ctzll(msk);
        cx = lane_bcast(bx, l0);
        cy = lane_bcast(by, l0);
        cz = lane_bcast(bz, l0);
    }
    // peeled final round: store centroid 511, then final flag
    if (FUSED) {
        if (lane >= 32 && lane < 35) {
            float v = (lane == 32) ? cx : ((lane == 33) ? cy : cz);
            unsigned* o = (unsigned*)ob + (SOUT - 1) * 3 + (lane - 32);
            __hip_atomic_store(o, __float_as_uint(v),
                               __ATOMIC_RELAXED, __HIP_MEMORY_SCOPE_AGENT);
        }
        if (lane == 32)                        // release: wave-wide vmcnt drain
            __hip_atomic_store(flagp, FMAGIC + 512u,
                               __ATOMIC_RELEASE, __HIP_MEMORY_SCOPE_AGENT);
    } else {
        if (lane == 0) {
            ob[(SOUT-1)*3+0] = cx; ob[(SOUT-1)*3+1] = cy; ob[(SOUT-1)*3+2] = cz;
        }
    }
}

// =================== group role (R6/R8 proven body; 1 wave, 1 query) =========
__device__ __forceinline__ void group_role(
        const float* __restrict__ xyz,  const float* __restrict__ points,
        const float* __restrict__ w1,   const float* __restrict__ b1,
        const float* __restrict__ w2,   const float* __restrict__ b2,
        const float* __restrict__ w3,   const float* __restrict__ b3,
        const float* __restrict__ new_xyz, float* __restrict__ new_points,
        const unsigned* flags, unsigned short* sidx, float* sh2,
        int lane, int q) {
    float wf3[32];
    {
        const float4* w3v = (const float4*)(w3 + lane * 32);
#pragma unroll
        for (int j = 0; j < 8; ++j) {
            float4 v = w3v[j];
            wf3[j*4+0] = v.x; wf3[j*4+1] = v.y; wf3[j*4+2] = v.z; wf3[j*4+3] = v.w;
        }
    }
    const float rb3 = b3[lane];
    const int b = q >> 9;
    const int s = q & (SOUT - 1);

    if (flags) {
        const unsigned* flagp = flags + (b << 6);   // 256 B apart
        if (lane == 0) {
            const unsigned tgt = FMAGIC + (unsigned)s + 1u;
            int polls = 0;
            for (;;) {
                unsigned v = __hip_atomic_load(flagp, __ATOMIC_ACQUIRE,
                                               __HIP_MEMORY_SCOPE_AGENT);
                if (v >= tgt && v <= FMAGIC + 512u) break;
                if (++polls > (1 << 18)) break;     // hang insurance
                __builtin_amdgcn_s_sleep(32);
            }
        }
        __threadfence();                            // wave-wide acquire
    }
    const unsigned* nx = (const unsigned*)new_xyz + (size_t)q * 3;
    const float qx = __uint_as_float(__hip_atomic_load(nx + 0, __ATOMIC_RELAXED, __HIP_MEMORY_SCOPE_AGENT));
    const float qy = __uint_as_float(__hip_atomic_load(nx + 1, __ATOMIC_RELAXED, __HIP_MEMORY_SCOPE_AGENT));
    const float qz = __uint_as_float(__hip_atomic_load(nx + 2, __ATOMIC_RELAXED, __HIP_MEMORY_SCOPE_AGENT));
    const float qs = __fadd_rn(__fadd_rn(__fmul_rn(qx,qx), __fmul_rn(qy,qy)), __fmul_rn(qz,qz));
    const float* xb = xyz    + (size_t)b * NPTS * 3;
    const float* pb = points + (size_t)b * 13 * NPTS;

    int cnt = 0;
    const unsigned long long lm = (1ull << lane) - 1ull;
    for (int r = 0; r < NPTS / 64; ++r) {
        int n = r * 64 + lane;
        float x = xb[n*3+0], y = xb[n*3+1], z = xb[n*3+2];
        float pn = __fadd_rn(__fadd_rn(__fmul_rn(x,x), __fmul_rn(y,y)), __fmul_rn(z,z));
        float dt = __fadd_rn(__fadd_rn(__fmul_rn(qx,x), __fmul_rn(qy,y)), __fmul_rn(qz,z));
        float sqr = __fsub_rn(__fadd_rn(qs, pn), __fmul_rn(2.0f, dt));
        bool sel = !(sqr > 0.04f);                 // keep iff sqr <= r^2 (f32)
        unsigned long long m = __ballot(sel);
        if (sel) sidx[cnt + __popcll(m & lm)] = (unsigned short)n;
        cnt += (int)__popcll(m);
    }
    const int K = cnt;                             // >= 1
    const int nfirst = (int)sidx[0];

    float mx = -3.0e38f;
    for (int tb = 0; tb < K; tb += 64) {
        int m = tb + lane;
        int n = (m < K) ? (int)sidx[m] : nfirst;   // pad = first neighbor
        float f[16];
        f[0] = xb[n*3+0] - qx;
        f[1] = xb[n*3+1] - qy;
        f[2] = xb[n*3+2] - qz;
#pragma unroll
        for (int c = 0; c < 13; ++c) f[3+c] = pb[c*NPTS + n];
        float h1[32];
#pragma unroll
        for (int o = 0; o < 32; ++o) {
            float acc = b1[o];                     // uniform -> s_load
            const float4* wr = (const float4*)(w1 + o*16);
#pragma unroll
            for (int c4 = 0; c4 < 4; ++c4) {
                float4 wv = wr[c4];
                acc = fmaf(f[c4*4+0], wv.x, acc);
                acc = fmaf(f[c4*4+1], wv.y, acc);
                acc = fmaf(f[c4*4+2], wv.z, acc);
                acc = fmaf(f[c4*4+3], wv.w, acc);
            }
            h1[o] = fmaxf(acc, 0.0f);
        }
        float h2[32];
#pragma unroll
        for (int o = 0; o < 32; ++o) {
            float acc = b2[o];                     // uniform -> s_load
            const float4* wr = (const float4*)(w2 + o*32);
#pragma unroll
            for (int c4 = 0; c4 < 8; ++c4) {
                float4 wv = wr[c4];
                acc = fmaf(h1[c4*4+0], wv.x, acc);
                acc = fmaf(h1[c4*4+1], wv.y, acc);
                acc = fmaf(h1[c4*4+2], wv.z, acc);
                acc = fmaf(h1[c4*4+3], wv.w, acc);
            }
            h2[o] = fmaxf(acc, 0.0f);
        }
        {
            float4* row = (float4*)(sh2 + lane * 36);
#pragma unroll
            for (int c4 = 0; c4 < 8; ++c4)
                row[c4] = make_float4(h2[c4*4+0], h2[c4*4+1], h2[c4*4+2], h2[c4*4+3]);
        }
        int rows = K - tb; if (rows > 64) rows = 64;
#pragma unroll 4
        for (int n2 = 0; n2 < rows; ++n2) {
            const float4* hr = (const float4*)(sh2 + n2 * 36);
            float acc = rb3;
#pragma unroll
            for (int c4 = 0; c4 < 8; ++c4) {
                float4 h = hr[c4];
                acc = fmaf(h.x, wf3[c4*4+0], acc);
                acc = fmaf(h.y, wf3[c4*4+1], acc);
                acc = fmaf(h.z, wf3[c4*4+2], acc);
                acc = fmaf(h.w, wf3[c4*4+3], acc);
            }
            mx = fmaxf(mx, acc);
        }
        // single wave: DS ops in-order -> no barrier between chunks
    }
    new_points[((size_t)b * 64 + lane) * SOUT + s] = mx;   // (B, 64, S)
}

// =================== fused kernel: blocks 0-1 fps (wave 0 only), 2-257 group =
__global__ __launch_bounds__(TB, 1) void fused_kernel(
        const float* __restrict__ xyz,  const float* __restrict__ points,
        const float* __restrict__ w1,   const float* __restrict__ b1,
        const float* __restrict__ w2,   const float* __restrict__ b2,
        const float* __restrict__ w3,   const float* __restrict__ b3,
        float* __restrict__ new_xyz, float* __restrict__ new_points,
        unsigned* flags, int far0, int far1) {
    __shared__ unsigned short s_sidx[4 * NPTS];
    __shared__ __align__(16) float s_sh2[4 * 64 * 36];
    const int blk = blockIdx.x;
    const int tid = threadIdx.x;
    if (blk < 2) {
        if (tid < 64) {                            // single-wave FPS, no barriers
            fps_role_sw<true>(xyz + (size_t)blk * NPTS * 3,
                              new_xyz + (size_t)blk * SOUT * 3,
                              flags + (blk << 6),
                              (blk == 0) ? far0 : far1, tid);
        }
        return;                                    // waves 1-3 exit immediately
    }
    const int lane = tid & 63;
    const int wvl  = tid >> 6;
    const int q    = (blk - 2) * 4 + wvl;          // 1024 queries
    group_role(xyz, points, w1, b1, w2, b2, w3, b3, new_xyz, new_points,
               flags, s_sidx + wvl * NPTS, s_sh2 + wvl * 64 * 36, lane, q);
}

// =================== fallback kernels (ws too small): serial path ============
__global__ __launch_bounds__(TB, 1) void fps_kernel(const float* __restrict__ xyz,
                                                    float* __restrict__ new_xyz,
                                                    int far0, int far1) {
    const int bg = blockIdx.x;
    if (threadIdx.x < 64)
        fps_role_sw<false>(xyz + (size_t)bg * NPTS * 3,
                           new_xyz + (size_t)bg * SOUT * 3,
                           nullptr, (bg == 0) ? far0 : far1, threadIdx.x);
}
__global__ __launch_bounds__(64, 1) void group_kernel(
        const float* __restrict__ xyz,  const float* __restrict__ points,
        const float* __restrict__ w1,   const float* __restrict__ b1,
        const float* __restrict__ w2,   const float* __restrict__ b2,
        const float* __restrict__ w3,   const float* __restrict__ b3,
        const float* __restrict__ new_xyz, float* __restrict__ new_points) {
    __shared__ unsigned short s_sidx[NPTS];
    __shared__ __align__(16) float s_sh2[64 * 36];
    group_role(xyz, points, w1, b1, w2, b2, w3, b3, new_xyz, new_points,
               nullptr, s_sidx, s_sh2, threadIdx.x, blockIdx.x);
}

// ---------------- host: threefry2x32 (JAX key(42) randint seed) --------------
static inline uint32_t rotl32(uint32_t x, int r) { return (x << r) | (x >> (32 - r)); }
static void threefry2x32_host(uint32_t k0, uint32_t k1, uint32_t& x0, uint32_t& x1) {
    const int R[2][4] = {{13,15,26,6},{17,29,16,24}};
    uint32_t ks[3] = {k0, k1, k0 ^ k1 ^ 0x1BD11BDAu};
    x0 += ks[0]; x1 += ks[1];
    for (int i = 0; i < 5; ++i) {
        for (int j = 0; j < 4; ++j) { x0 += x1; x1 = rotl32(x1, R[i & 1][j]); x1 ^= x0; }
        x0 += ks[(i + 1) % 3];
        x1 += ks[(i + 2) % 3] + (uint32_t)(i + 1);
    }
}

extern "C" void kernel_launch(void* const* d_in, const int* in_sizes, int n_in,
                              void* d_out, int out_size, void* d_ws, size_t ws_size,
                              hipStream_t stream) {
    const float* xyz    = (const float*)d_in[0];
    const float* points = (const float*)d_in[1];
    const float* w1 = (const float*)d_in[2];
    const float* b1 = (const float*)d_in[3];
    const float* w2 = (const float*)d_in[4];
    const float* b2 = (const float*)d_in[5];
    const float* w3 = (const float*)d_in[6];
    const float* b3 = (const float*)d_in[7];
    float* out        = (float*)d_out;
    float* new_xyz    = out;                      // (B, S, 3)
    float* new_points = out + NB * SOUT * 3;      // (B, 64, S)

    // jax.random.randint(key(42), (2,), 0, 2048), modern JAX
    // (jax_threefry_partitionable=True): _randint splits the key first:
    //   k1, k2 = split(key); result = random_bits(k2, 32, (2,)) & 2047
    // foldlike split: k2 = threefry((0,42),(0,1)) full pair.
    // partitionable bits: elem i = xor-halves of threefry(k2, (0,i)).
    // (VERIFIED passing in rounds 3-9 — do not change.)
    uint32_t k2a = 0, k2b = 1; threefry2x32_host(0u, 42u, k2a, k2b);
    uint32_t u0 = 0, u1 = 0;  threefry2x32_host(k2a, k2b, u0, u1);
    uint32_t v0 = 0, v1 = 1;  threefry2x32_host(k2a, k2b, v0, v1);
    int far0 = (int)((u0 ^ u1) & (NPTS - 1));
    int far1 = (int)((v0 ^ v1) & (NPTS - 1));

    if (ws_size >= 512) {
        // fused producer-consumer: flags in d_ws (poison 0xAAAAAAAA < FMAGIC
        // -> consumers spin until this launch's publisher writes).
        hipLaunchKernelGGL(fused_kernel, dim3(2 + NB * SOUT / 4), dim3(TB), 0, stream,
                           xyz, points, w1, b1, w2, b2, w3, b3,
                           new_xyz, new_points, (unsigned*)d_ws, far0, far1);
    } else {
        hipLaunchKernelGGL(fps_kernel, dim3(NB), dim3(TB), 0, stream,
                           xyz, new_xyz, far0, far1);
        hipLaunchKernelGGL(group_kernel, dim3(NB * SOUT), dim3(64), 0, stream,
                           xyz, points, w1, b1, w2, b2, w3, b3, new_xyz, new_points);
    }
}

// Round 2
// 460.782 us; speedup vs baseline: 1.1574x; 1.1574x over previous
//
#include <hip/hip_runtime.h>
#include <stdint.h>

#define NPTS 2048
#define SOUT 512
#define NB   2
#define TB   512           // 8 waves per block
#define NW   8             // fps waves per batch
#define PPT  4             // fps points per lane
#define GW   4             // active group waves per group block
#define FMAGIC 0xC0DE0000u

typedef float vf2 __attribute__((ext_vector_type(2)));

// ---- DPP wave64 max-reduce (nonneg values; bound_ctrl zero-fill is safe) ----
__device__ __forceinline__ float wave_allmax_f32(float v) {
    int x = __float_as_int(v); int t;
    t = __builtin_amdgcn_update_dpp(x, x, 0x111, 0xF, 0xF, true); v = fmaxf(v, __int_as_float(t)); x = __float_as_int(v);
    t = __builtin_amdgcn_update_dpp(x, x, 0x112, 0xF, 0xF, true); v = fmaxf(v, __int_as_float(t)); x = __float_as_int(v);
    t = __builtin_amdgcn_update_dpp(x, x, 0x114, 0xF, 0xF, true); v = fmaxf(v, __int_as_float(t)); x = __float_as_int(v);
    t = __builtin_amdgcn_update_dpp(x, x, 0x118, 0xF, 0xF, true); v = fmaxf(v, __int_as_float(t)); x = __float_as_int(v);
    t = __builtin_amdgcn_update_dpp(x, x, 0x142, 0xA, 0xF, true); v = fmaxf(v, __int_as_float(t)); x = __float_as_int(v);
    t = __builtin_amdgcn_update_dpp(x, x, 0x143, 0xC, 0xF, true); v = fmaxf(v, __int_as_float(t)); x = __float_as_int(v);
    return __int_as_float(__builtin_amdgcn_readlane(x, 63));
}
__device__ __forceinline__ float4 sel4(bool c, float4 A, float4 B) {
    float4 r;
    r.x = c ? A.x : B.x; r.y = c ? A.y : B.y;
    r.z = c ? A.z : B.z; r.w = c ? A.w : B.w;
    return r;
}

// =================== FPS role — 8 waves, 4 pts/lane ==========================
// Round = distance update (2 vf2) + small local select tree + DPP wave reduce
// + winning-lane ds_write of {v,x,y,z} + barrier + 8-slot broadcast-read merge.
// Tie-break preserved: global index n = t*4 + slot; within-vf2 .x wins (>=),
// vf2[0] beats vf2[1] (>=), ballot picks lowest lane, merge tree prefers
// lower wave (a_hi.x > a_lo.x keeps lo on ties). Arithmetic identical to the
// proven version (fp contract off, rn each op, fminf chain).
// Publisher (FUSED, wave 7): tri-lane relaxed centroid store each round;
// release flag every 16 rounds BEFORE that round's stores (covers rounds < s;
// the release's wave-wide vmcnt(0) drains all prior lanes' stores).
template<bool FUSED>
__device__ __forceinline__ void fps_role8(const float* __restrict__ xb,
                                          float* __restrict__ ob,
                                          unsigned* flagp, int far,
                                          float4* slot /*2*NW*/, float* scf,
                                          int t) {
    const int lane = t & 63;
    const int wvl  = t >> 6;
    vf2 PX[2], PY[2], PZ[2], DD[2];
    {
        const float4* src = (const float4*)(xb + (size_t)t * (PPT * 3));
        float4 a  = src[0];
        float4 b4 = src[1];
        float4 c4 = src[2];
        // local points 0..3: (a.x,a.y,a.z) (a.w,b.x,b.y) (b.z,b.w,c.x) (c.y,c.z,c.w)
        PX[0].x = a.x;  PY[0].x = a.y;  PZ[0].x = a.z;
        PX[0].y = a.w;  PY[0].y = b4.x; PZ[0].y = b4.y;
        PX[1].x = b4.z; PY[1].x = b4.w; PZ[1].x = c4.x;
        PX[1].y = c4.y; PY[1].y = c4.z; PZ[1].y = c4.w;
        DD[0].x = 1e10f; DD[0].y = 1e10f;
        DD[1].x = 1e10f; DD[1].y = 1e10f;
    }
    float cx = xb[far*3+0], cy = xb[far*3+1], cz = xb[far*3+2];

    for (int s = 0; s < SOUT - 1; ++s) {
        if (FUSED) {
            if (wvl == NW - 1) {
                if (lane == 32 && s >= 16 && (s & 15) == 0)   // covers rounds < s
                    __hip_atomic_store(flagp, FMAGIC + (unsigned)s,
                                       __ATOMIC_RELEASE, __HIP_MEMORY_SCOPE_AGENT);
                if (lane >= 32 && lane < 35) {                // one vmem, 3 lanes
                    float v = (lane == 32) ? cx : ((lane == 33) ? cy : cz);
                    unsigned* o = (unsigned*)ob + s * 3 + (lane - 32);
                    __hip_atomic_store(o, __float_as_uint(v),
                                       __ATOMIC_RELAXED, __HIP_MEMORY_SCOPE_AGENT);
                }
            }
        } else {
            if (t == 0) { scf[s*3+0] = cx; scf[s*3+1] = cy; scf[s*3+2] = cz; }
        }
        // --- distance update (identical op order/rounding to proven kernel)
        {
#pragma clang fp contract(off)
            vf2 vcx; vcx.x = cx; vcx.y = cx;
            vf2 vcy; vcy.x = cy; vcy.y = cy;
            vf2 vcz; vcz.x = cz; vcz.y = cz;
#pragma unroll
            for (int j = 0; j < 2; ++j) {
                vf2 dx = PX[j] - vcx;
                vf2 dy = PY[j] - vcy;
                vf2 dz = PZ[j] - vcz;
                vf2 d2 = (dx*dx + dy*dy) + dz*dz;   // ((xx+yy)+zz), rn each
                DD[j].x = fminf(DD[j].x, d2.x);
                DD[j].y = fminf(DD[j].y, d2.y);
            }
        }
        // --- local argmax, coords carried; >= keeps earlier index
        bool la = DD[0].x >= DD[0].y;
        float va = la ? DD[0].x : DD[0].y;
        float ax = la ? PX[0].x : PX[0].y;
        float ay = la ? PY[0].x : PY[0].y;
        float az = la ? PZ[0].x : PZ[0].y;
        bool lb = DD[1].x >= DD[1].y;
        float vb = lb ? DD[1].x : DD[1].y;
        float ex = lb ? PX[1].x : PX[1].y;
        float ey = lb ? PY[1].x : PY[1].y;
        float ez = lb ? PZ[1].x : PZ[1].y;
        bool gm = va >= vb;
        float bv = gm ? va : vb;
        float bx = gm ? ax : ex;
        float by = gm ? ay : ey;
        float bz = gm ? az : ez;
        // --- wave reduce; first-occurrence lane writes its slot directly
        float wmax = wave_allmax_f32(bv);
        unsigned long long msk = __ballot(bv == wmax);
        int l0 = (int)__builtin_ctzll(msk);
        const int par = s & 1;
        if (lane == l0) slot[par*NW + wvl] = make_float4(wmax, bx, by, bz);
        if (FUSED) {
            // lgkm-only drain (slot handoff) -> publisher vmem stays in flight
            __builtin_amdgcn_s_waitcnt(0xC07F);   // vmcnt(63) exp(7) lgkmcnt(0)
            __builtin_amdgcn_s_barrier();
        } else {
            __syncthreads();
        }
        // --- 8-slot merge; same-address lane reads = LDS broadcast, no conflict
        float4 a0 = slot[par*NW + 0];
        float4 a1 = slot[par*NW + 1];
        float4 a2 = slot[par*NW + 2];
        float4 a3 = slot[par*NW + 3];
        float4 a4 = slot[par*NW + 4];
        float4 a5 = slot[par*NW + 5];
        float4 a6 = slot[par*NW + 6];
        float4 a7 = slot[par*NW + 7];
        float4 m01 = sel4(a1.x > a0.x, a1, a0);
        float4 m23 = sel4(a3.x > a2.x, a3, a2);
        float4 m45 = sel4(a5.x > a4.x, a5, a4);
        float4 m67 = sel4(a7.x > a6.x, a7, a6);
        float4 mA  = sel4(m23.x > m01.x, m23, m01);
        float4 mB  = sel4(m67.x > m45.x, m67, m45);
        float4 mf  = sel4(mB.x > mA.x, mB, mA);
        cx = mf.y; cy = mf.z; cz = mf.w;
    }
    // peeled final round: store centroid 511, then final flag
    if (FUSED) {
        if (wvl == NW - 1) {
            if (lane >= 32 && lane < 35) {
                float v = (lane == 32) ? cx : ((lane == 33) ? cy : cz);
                unsigned* o = (unsigned*)ob + (SOUT - 1) * 3 + (lane - 32);
                __hip_atomic_store(o, __float_as_uint(v),
                                   __ATOMIC_RELAXED, __HIP_MEMORY_SCOPE_AGENT);
            }
            if (lane == 32)                    // release: wave-wide vmcnt drain
                __hip_atomic_store(flagp, FMAGIC + 512u,
                                   __ATOMIC_RELEASE, __HIP_MEMORY_SCOPE_AGENT);
        }
    } else {
        if (t == 0) {
            scf[(SOUT-1)*3+0] = cx; scf[(SOUT-1)*3+1] = cy; scf[(SOUT-1)*3+2] = cz;
        }
        __syncthreads();
        for (int i = t; i < SOUT * 3; i += TB) ob[i] = scf[i];
    }
}

// =================== group role (R6/R8 proven body; 1 wave, 1 query) =========
__device__ __forceinline__ void group_role(
        const float* __restrict__ xyz,  const float* __restrict__ points,
        const float* __restrict__ w1,   const float* __restrict__ b1,
        const float* __restrict__ w2,   const float* __restrict__ b2,
        const float* __restrict__ w3,   const float* __restrict__ b3,
        const float* __restrict__ new_xyz, float* __restrict__ new_points,
        const unsigned* flags, unsigned short* sidx, float* sh2,
        int lane, int q) {
    float wf3[32];
    {
        const float4* w3v = (const float4*)(w3 + lane * 32);
#pragma unroll
        for (int j = 0; j < 8; ++j) {
            float4 v = w3v[j];
            wf3[j*4+0] = v.x; wf3[j*4+1] = v.y; wf3[j*4+2] = v.z; wf3[j*4+3] = v.w;
        }
    }
    const float rb3 = b3[lane];
    const int b = q >> 9;
    const int s = q & (SOUT - 1);

    if (flags) {
        const unsigned* flagp = flags + (b << 6);   // 256 B apart
        if (lane == 0) {
            const unsigned tgt = FMAGIC + (unsigned)s + 1u;
            int polls = 0;
            for (;;) {
                unsigned v = __hip_atomic_load(flagp, __ATOMIC_ACQUIRE,
                                               __HIP_MEMORY_SCOPE_AGENT);
                if (v >= tgt && v <= FMAGIC + 512u) break;
                if (++polls > (1 << 18)) break;     // hang insurance
                __builtin_amdgcn_s_sleep(32);
            }
        }
        __threadfence();                            // wave-wide acquire
    }
    const unsigned* nx = (const unsigned*)new_xyz + (size_t)q * 3;
    const float qx = __uint_as_float(__hip_atomic_load(nx + 0, __ATOMIC_RELAXED, __HIP_MEMORY_SCOPE_AGENT));
    const float qy = __uint_as_float(__hip_atomic_load(nx + 1, __ATOMIC_RELAXED, __HIP_MEMORY_SCOPE_AGENT));
    const float qz = __uint_as_float(__hip_atomic_load(nx + 2, __ATOMIC_RELAXED, __HIP_MEMORY_SCOPE_AGENT));
    const float qs = __fadd_rn(__fadd_rn(__fmul_rn(qx,qx), __fmul_rn(qy,qy)), __fmul_rn(qz,qz));
    const float* xb = xyz    + (size_t)b * NPTS * 3;
    const float* pb = points + (size_t)b * 13 * NPTS;

    int cnt = 0;
    const unsigned long long lm = (1ull << lane) - 1ull;
    for (int r = 0; r < NPTS / 64; ++r) {
        int n = r * 64 + lane;
        float x = xb[n*3+0], y = xb[n*3+1], z = xb[n*3+2];
        float pn = __fadd_rn(__fadd_rn(__fmul_rn(x,x), __fmul_rn(y,y)), __fmul_rn(z,z));
        float dt = __fadd_rn(__fadd_rn(__fmul_rn(qx,x), __fmul_rn(qy,y)), __fmul_rn(qz,z));
        float sqr = __fsub_rn(__fadd_rn(qs, pn), __fmul_rn(2.0f, dt));
        bool sel = !(sqr > 0.04f);                 // keep iff sqr <= r^2 (f32)
        unsigned long long m = __ballot(sel);
        if (sel) sidx[cnt + __popcll(m & lm)] = (unsigned short)n;
        cnt += (int)__popcll(m);
    }
    const int K = cnt;                             // >= 1
    const int nfirst = (int)sidx[0];

    float mx = -3.0e38f;
    for (int tb = 0; tb < K; tb += 64) {
        int m = tb + lane;
        int n = (m < K) ? (int)sidx[m] : nfirst;   // pad = first neighbor
        float f[16];
        f[0] = xb[n*3+0] - qx;
        f[1] = xb[n*3+1] - qy;
        f[2] = xb[n*3+2] - qz;
#pragma unroll
        for (int c = 0; c < 13; ++c) f[3+c] = pb[c*NPTS + n];
        float h1[32];
#pragma unroll
        for (int o = 0; o < 32; ++o) {
            float acc = b1[o];                     // uniform -> s_load
            const float4* wr = (const float4*)(w1 + o*16);
#pragma unroll
            for (int c4 = 0; c4 < 4; ++c4) {
                float4 wv = wr[c4];
                acc = fmaf(f[c4*4+0], wv.x, acc);
                acc = fmaf(f[c4*4+1], wv.y, acc);
                acc = fmaf(f[c4*4+2], wv.z, acc);
                acc = fmaf(f[c4*4+3], wv.w, acc);
            }
            h1[o] = fmaxf(acc, 0.0f);
        }
        float h2[32];
#pragma unroll
        for (int o = 0; o < 32; ++o) {
            float acc = b2[o];                     // uniform -> s_load
            const float4* wr = (const float4*)(w2 + o*32);
#pragma unroll
            for (int c4 = 0; c4 < 8; ++c4) {
                float4 wv = wr[c4];
                acc = fmaf(h1[c4*4+0], wv.x, acc);
                acc = fmaf(h1[c4*4+1], wv.y, acc);
                acc = fmaf(h1[c4*4+2], wv.z, acc);
                acc = fmaf(h1[c4*4+3], wv.w, acc);
            }
            h2[o] = fmaxf(acc, 0.0f);
        }
        {
            float4* row = (float4*)(sh2 + lane * 36);
#pragma unroll
            for (int c4 = 0; c4 < 8; ++c4)
                row[c4] = make_float4(h2[c4*4+0], h2[c4*4+1], h2[c4*4+2], h2[c4*4+3]);
        }
        int rows = K - tb; if (rows > 64) rows = 64;
#pragma unroll 4
        for (int n2 = 0; n2 < rows; ++n2) {
            const float4* hr = (const float4*)(sh2 + n2 * 36);
            float acc = rb3;
#pragma unroll
            for (int c4 = 0; c4 < 8; ++c4) {
                float4 h = hr[c4];
                acc = fmaf(h.x, wf3[c4*4+0], acc);
                acc = fmaf(h.y, wf3[c4*4+1], acc);
                acc = fmaf(h.z, wf3[c4*4+2], acc);
                acc = fmaf(h.w, wf3[c4*4+3], acc);
            }
            mx = fmaxf(mx, acc);
        }
        // single wave: DS ops in-order -> no barrier between chunks
    }
    new_points[((size_t)b * 64 + lane) * SOUT + s] = mx;   // (B, 64, S)
}

// ========== fused kernel: blocks 0-1 fps (8 waves), 2-129 group (4 waves) ====
// 130 blocks x 512 threads: 1 block/CU -> all blocks resident (no deadlock).
// FPS blocks own a full CU: 2 fps waves per SIMD fill dependency bubbles.
// Each group wave serves two queries with the SAME s: batch 0 then batch 1
// (batch 1's flag has progressed equally by then -> negligible second wait).
__global__ __launch_bounds__(TB, 1) void fused_kernel(
        const float* __restrict__ xyz,  const float* __restrict__ points,
        const float* __restrict__ w1,   const float* __restrict__ b1,
        const float* __restrict__ w2,   const float* __restrict__ b2,
        const float* __restrict__ w3,   const float* __restrict__ b3,
        float* __restrict__ new_xyz, float* __restrict__ new_points,
        unsigned* flags, int far0, int far1) {
    __shared__ float4 s_slot[2 * NW];
    __shared__ unsigned short s_sidx[GW * NPTS];
    __shared__ __align__(16) float s_sh2[GW * 64 * 36];
    const int blk = blockIdx.x;
    const int tid = threadIdx.x;
    if (blk < 2) {
        fps_role8<true>(xyz + (size_t)blk * NPTS * 3,
                        new_xyz + (size_t)blk * SOUT * 3,
                        flags + (blk << 6),
                        (blk == 0) ? far0 : far1,
                        s_slot, nullptr, tid);
        return;
    }
    const int lane = tid & 63;
    const int wvl  = tid >> 6;
    if (wvl >= GW) return;                         // waves 4-7 idle-exit
    const int widx = (blk - 2) * GW + wvl;         // 0..511 (= s)
    unsigned short* sx = s_sidx + wvl * NPTS;
    float* sh = s_sh2 + (size_t)wvl * 64 * 36;
    group_role(xyz, points, w1, b1, w2, b2, w3, b3, new_xyz, new_points,
               flags, sx, sh, lane, widx);         // batch 0, s = widx
    group_role(xyz, points, w1, b1, w2, b2, w3, b3, new_xyz, new_points,
               flags, sx, sh, lane, widx + 512);   // batch 1, same s
}

// =================== fallback kernels (ws too small): serial path ============
__global__ __launch_bounds__(TB, 1) void fps_kernel(const float* __restrict__ xyz,
                                                    float* __restrict__ new_xyz,
                                                    int far0, int far1) {
    __shared__ float4 s_slot[2 * NW];
    __shared__ __align__(16) float s_scf[SOUT * 3];
    const int bg = blockIdx.x;
    fps_role8<false>(xyz + (size_t)bg * NPTS * 3, new_xyz + (size_t)bg * SOUT * 3,
                     nullptr, (bg == 0) ? far0 : far1, s_slot, s_scf, threadIdx.x);
}
__global__ __launch_bounds__(64, 1) void group_kernel(
        const float* __restrict__ xyz,  const float* __restrict__ points,
        const float* __restrict__ w1,   const float* __restrict__ b1,
        const float* __restrict__ w2,   const float* __restrict__ b2,
        const float* __restrict__ w3,   const float* __restrict__ b3,
        const float* __restrict__ new_xyz, float* __restrict__ new_points) {
    __shared__ unsigned short s_sidx[NPTS];
    __shared__ __align__(16) float s_sh2[64 * 36];
    group_role(xyz, points, w1, b1, w2, b2, w3, b3, new_xyz, new_points,
               nullptr, s_sidx, s_sh2, threadIdx.x, blockIdx.x);
}

// ---------------- host: threefry2x32 (JAX key(42) randint seed) --------------
static inline uint32_t rotl32(uint32_t x, int r) { return (x << r) | (x >> (32 - r)); }
static void threefry2x32_host(uint32_t k0, uint32_t k1, uint32_t& x0, uint32_t& x1) {
    const int R[2][4] = {{13,15,26,6},{17,29,16,24}};
    uint32_t ks[3] = {k0, k1, k0 ^ k1 ^ 0x1BD11BDAu};
    x0 += ks[0]; x1 += ks[1];
    for (int i = 0; i < 5; ++i) {
        for (int j = 0; j < 4; ++j) { x0 += x1; x1 = rotl32(x1, R[i & 1][j]); x1 ^= x0; }
        x0 += ks[(i + 1) % 3];
        x1 += ks[(i + 2) % 3] + (uint32_t)(i + 1);
    }
}

extern "C" void kernel_launch(void* const* d_in, const int* in_sizes, int n_in,
                              void* d_out, int out_size, void* d_ws, size_t ws_size,
                              hipStream_t stream) {
    const float* xyz    = (const float*)d_in[0];
    const float* points = (const float*)d_in[1];
    const float* w1 = (const float*)d_in[2];
    const float* b1 = (const float*)d_in[3];
    const float* w2 = (const float*)d_in[4];
    const float* b2 = (const float*)d_in[5];
    const float* w3 = (const float*)d_in[6];
    const float* b3 = (const float*)d_in[7];
    float* out        = (float*)d_out;
    float* new_xyz    = out;                      // (B, S, 3)
    float* new_points = out + NB * SOUT * 3;      // (B, 64, S)

    // jax.random.randint(key(42), (2,), 0, 2048), modern JAX
    // (jax_threefry_partitionable=True): _randint splits the key first:
    //   k1, k2 = split(key); result = random_bits(k2, 32, (2,)) & 2047
    // foldlike split: k2 = threefry((0,42),(0,1)) full pair.
    // partitionable bits: elem i = xor-halves of threefry(k2, (0,i)).
    // (VERIFIED passing in rounds 3-9 — do not change.)
    uint32_t k2a = 0, k2b = 1; threefry2x32_host(0u, 42u, k2a, k2b);
    uint32_t u0 = 0, u1 = 0;  threefry2x32_host(k2a, k2b, u0, u1);
    uint32_t v0 = 0, v1 = 1;  threefry2x32_host(k2a, k2b, v0, v1);
    int far0 = (int)((u0 ^ u1) & (NPTS - 1));
    int far1 = (int)((v0 ^ v1) & (NPTS - 1));

    if (ws_size >= 512) {
        // fused producer-consumer: flags in d_ws (poison 0xAAAAAAAA < FMAGIC
        // -> consumers spin until this launch's publisher writes).
        hipLaunchKernelGGL(fused_kernel, dim3(2 + NB * SOUT / (2 * GW)), dim3(TB), 0, stream,
                           xyz, points, w1, b1, w2, b2, w3, b3,
                           new_xyz, new_points, (unsigned*)d_ws, far0, far1);
    } else {
        hipLaunchKernelGGL(fps_kernel, dim3(NB), dim3(TB), 0, stream,
                           xyz, new_xyz, far0, far1);
        hipLaunchKernelGGL(group_kernel, dim3(NB * SOUT), dim3(64), 0, stream,
                           xyz, points, w1, b1, w2, b2, w3, b3, new_xyz, new_points);
    }
}

// Round 3
// 344.809 us; speedup vs baseline: 1.5467x; 1.3363x over previous
//
#include <hip/hip_runtime.h>
#include <stdint.h>

#define NPTS 2048
#define SOUT 512
#define NB   2
#define TB   256
#define PPT  8             // fps: points per lane, k-major
#define NW   4             // fps: waves per batch
#define FMAGIC 0xC0DE0000u

typedef float vf2 __attribute__((ext_vector_type(2)));

// ---- DPP wave64 max-reduce (nonneg values; bound_ctrl zero-fill is safe) ----
__device__ __forceinline__ float wave_allmax_f32(float v) {
    int x = __float_as_int(v); int t;
    t = __builtin_amdgcn_update_dpp(x, x, 0x111, 0xF, 0xF, true); v = fmaxf(v, __int_as_float(t)); x = __float_as_int(v);
    t = __builtin_amdgcn_update_dpp(x, x, 0x112, 0xF, 0xF, true); v = fmaxf(v, __int_as_float(t)); x = __float_as_int(v);
    t = __builtin_amdgcn_update_dpp(x, x, 0x114, 0xF, 0xF, true); v = fmaxf(v, __int_as_float(t)); x = __float_as_int(v);
    t = __builtin_amdgcn_update_dpp(x, x, 0x118, 0xF, 0xF, true); v = fmaxf(v, __int_as_float(t)); x = __float_as_int(v);
    t = __builtin_amdgcn_update_dpp(x, x, 0x142, 0xA, 0xF, true); v = fmaxf(v, __int_as_float(t)); x = __float_as_int(v);
    t = __builtin_amdgcn_update_dpp(x, x, 0x143, 0xC, 0xF, true); v = fmaxf(v, __int_as_float(t)); x = __float_as_int(v);
    return __int_as_float(__builtin_amdgcn_readlane(x, 63));
}
__device__ __forceinline__ float4 sel4(bool c, float4 A, float4 B) {
    float4 r;
    r.x = c ? A.x : B.x; r.y = c ? A.y : B.y;
    r.z = c ? A.z : B.z; r.w = c ? A.w : B.w;
    return r;
}

// =================== FPS role (4 waves x 8 pts/lane; shortened chain) ========
// Per round: dist update -> value-only fmax tree (depth 3) -> DPP wave reduce
// -> ballot lowest-lane -> late coord select (lowest slot j with DD[j]==wmax,
// exact since fmax/fmin return operands bitwise) -> winner lane writes its
// slot directly (no readlane broadcasts) -> barrier -> 4-slot merge.
// Tie-break = lowest global index n = t*8 + j: lowest slot (descending guarded
// chain, slot 0 applied last), lowest lane (ctz of ballot), lowest wave
// (merge keeps a0 on ties). Distance arithmetic identical to proven version
// (fp contract off, rn each op, fminf chain).
// Publisher (FUSED, wave 3): tri-lane relaxed centroid store each round;
// release flag every 16 rounds BEFORE that round's stores (covers rounds < s;
// the release's wave-wide vmcnt(0) drains all prior lanes' stores).
template<bool FUSED>
__device__ __forceinline__ void fps_role(const float* __restrict__ xb,
                                         float* __restrict__ ob,
                                         unsigned* flagp, int far,
                                         float4* slot /*2*NW*/, float* scf,
                                         int t) {
    const int lane = t & 63;
    const int wvl  = t >> 6;
    float v24[24];
    {
        const float4* src = (const float4*)(xb + t * PPT * 3);
#pragma unroll
        for (int j = 0; j < 6; ++j) {
            float4 a = src[j];
            v24[j*4+0] = a.x; v24[j*4+1] = a.y; v24[j*4+2] = a.z; v24[j*4+3] = a.w;
        }
    }
    vf2 PX[4], PY[4], PZ[4], DD[4];
#pragma unroll
    for (int j = 0; j < 4; ++j) {
        PX[j].x = v24[(2*j)*3+0]; PX[j].y = v24[(2*j+1)*3+0];
        PY[j].x = v24[(2*j)*3+1]; PY[j].y = v24[(2*j+1)*3+1];
        PZ[j].x = v24[(2*j)*3+2]; PZ[j].y = v24[(2*j+1)*3+2];
        DD[j].x = 1e10f; DD[j].y = 1e10f;
    }
    float cx = xb[far*3+0], cy = xb[far*3+1], cz = xb[far*3+2];

    for (int s = 0; s < SOUT - 1; ++s) {
        if (FUSED) {
            if (wvl == 3) {
                if (lane == 32 && s >= 16 && (s & 15) == 0)   // covers rounds < s
                    __hip_atomic_store(flagp, FMAGIC + (unsigned)s,
                                       __ATOMIC_RELEASE, __HIP_MEMORY_SCOPE_AGENT);
                if (lane >= 32 && lane < 35) {                // one vmem, 3 lanes
                    float v = (lane == 32) ? cx : ((lane == 33) ? cy : cz);
                    unsigned* o = (unsigned*)ob + s * 3 + (lane - 32);
                    __hip_atomic_store(o, __float_as_uint(v),
                                       __ATOMIC_RELAXED, __HIP_MEMORY_SCOPE_AGENT);
                }
            }
        } else {
            if (t == 0) { scf[s*3+0] = cx; scf[s*3+1] = cy; scf[s*3+2] = cz; }
        }
        {
#pragma clang fp contract(off)
            vf2 vcx; vcx.x = cx; vcx.y = cx;
            vf2 vcy; vcy.x = cy; vcy.y = cy;
            vf2 vcz; vcz.x = cz; vcz.y = cz;
#pragma unroll
            for (int j = 0; j < 4; ++j) {
                vf2 dx = PX[j] - vcx;
                vf2 dy = PY[j] - vcy;
                vf2 dz = PZ[j] - vcz;
                vf2 d2 = (dx*dx + dy*dy) + dz*dz;   // ((xx+yy)+zz), rn each
                DD[j].x = fminf(DD[j].x, d2.x);
                DD[j].y = fminf(DD[j].y, d2.y);
            }
        }
        // --- value-only in-lane reduce (depth 3, 7 fmax)
        float m0 = fmaxf(DD[0].x, DD[0].y);
        float m1 = fmaxf(DD[1].x, DD[1].y);
        float m2 = fmaxf(DD[2].x, DD[2].y);
        float m3 = fmaxf(DD[3].x, DD[3].y);
        float bv = fmaxf(fmaxf(m0, m1), fmaxf(m2, m3));
        // --- wave reduce + first-occurrence lane
        float wmax = wave_allmax_f32(bv);
        unsigned long long msk = __ballot(bv == wmax);
        int l0 = (int)__builtin_ctzll(msk);
        // --- late coord select: lowest slot j with DD[j]==wmax (descending
        //     guarded updates; slot 0 applied last -> lowest index wins).
        //     Exact: fmax/fmin return an operand bitwise; no NaNs here.
        float bx = PX[3].y, by = PY[3].y, bz = PZ[3].y;            // slot 7
        { bool c = DD[3].x == wmax; bx = c?PX[3].x:bx; by = c?PY[3].x:by; bz = c?PZ[3].x:bz; } // 6
        { bool c = DD[2].y == wmax; bx = c?PX[2].y:bx; by = c?PY[2].y:by; bz = c?PZ[2].y:bz; } // 5
        { bool c = DD[2].x == wmax; bx = c?PX[2].x:bx; by = c?PY[2].x:by; bz = c?PZ[2].x:bz; } // 4
        { bool c = DD[1].y == wmax; bx = c?PX[1].y:bx; by = c?PY[1].y:by; bz = c?PZ[1].y:bz; } // 3
        { bool c = DD[1].x == wmax; bx = c?PX[1].x:bx; by = c?PY[1].x:by; bz = c?PZ[1].x:bz; } // 2
        { bool c = DD[0].y == wmax; bx = c?PX[0].y:bx; by = c?PY[0].y:by; bz = c?PZ[0].y:bz; } // 1
        { bool c = DD[0].x == wmax; bx = c?PX[0].x:bx; by = c?PY[0].x:by; bz = c?PZ[0].x:bz; } // 0
        const int par = s & 1;
        if (lane == l0) slot[par*NW + wvl] = make_float4(wmax, bx, by, bz);
        if (FUSED) {
            // lgkm-only drain (slot handoff) -> publisher vmem stays in flight
            __builtin_amdgcn_s_waitcnt(0xC07F);   // vmcnt(63) exp(7) lgkmcnt(0)
            __builtin_amdgcn_s_barrier();
        } else {
            __syncthreads();
        }
        // depth-2 merge tree; all ties -> lower wave = lower global index
        float4 a0 = slot[par*NW + 0];
        float4 a1 = slot[par*NW + 1];
        float4 a2 = slot[par*NW + 2];
        float4 a3 = slot[par*NW + 3];
        float4 m01 = sel4(a1.x > a0.x, a1, a0);
        float4 m23 = sel4(a3.x > a2.x, a3, a2);
        float4 mf  = sel4(m23.x > m01.x, m23, m01);
        cx = mf.y; cy = mf.z; cz = mf.w;
    }
    // peeled final round: store centroid 511, then final flag
    if (FUSED) {
        if (wvl == 3) {
            if (lane >= 32 && lane < 35) {
                float v = (lane == 32) ? cx : ((lane == 33) ? cy : cz);
                unsigned* o = (unsigned*)ob + (SOUT - 1) * 3 + (lane - 32);
                __hip_atomic_store(o, __float_as_uint(v),
                                   __ATOMIC_RELAXED, __HIP_MEMORY_SCOPE_AGENT);
            }
            if (lane == 32)                    // release: wave-wide vmcnt drain
                __hip_atomic_store(flagp, FMAGIC + 512u,
                                   __ATOMIC_RELEASE, __HIP_MEMORY_SCOPE_AGENT);
        }
    } else {
        if (t == 0) {
            scf[(SOUT-1)*3+0] = cx; scf[(SOUT-1)*3+1] = cy; scf[(SOUT-1)*3+2] = cz;
        }
        __syncthreads();
        for (int i = t; i < SOUT * 3; i += TB) ob[i] = scf[i];
    }
}

// =================== group role (R6/R8 proven body; 1 wave, 1 query) =========
__device__ __forceinline__ void group_role(
        const float* __restrict__ xyz,  const float* __restrict__ points,
        const float* __restrict__ w1,   const float* __restrict__ b1,
        const float* __restrict__ w2,   const float* __restrict__ b2,
        const float* __restrict__ w3,   const float* __restrict__ b3,
        const float* __restrict__ new_xyz, float* __restrict__ new_points,
        const unsigned* flags, unsigned short* sidx, float* sh2,
        int lane, int q) {
    float wf3[32];
    {
        const float4* w3v = (const float4*)(w3 + lane * 32);
#pragma unroll
        for (int j = 0; j < 8; ++j) {
            float4 v = w3v[j];
            wf3[j*4+0] = v.x; wf3[j*4+1] = v.y; wf3[j*4+2] = v.z; wf3[j*4+3] = v.w;
        }
    }
    const float rb3 = b3[lane];
    const int b = q >> 9;
    const int s = q & (SOUT - 1);

    if (flags) {
        const unsigned* flagp = flags + (b << 6);   // 256 B apart
        if (lane == 0) {
            const unsigned tgt = FMAGIC + (unsigned)s + 1u;
            int polls = 0;
            for (;;) {
                unsigned v = __hip_atomic_load(flagp, __ATOMIC_ACQUIRE,
                                               __HIP_MEMORY_SCOPE_AGENT);
                if (v >= tgt && v <= FMAGIC + 512u) break;
                if (++polls > (1 << 18)) break;     // hang insurance
                __builtin_amdgcn_s_sleep(32);
            }
        }
        __threadfence();                            // wave-wide acquire
    }
    const unsigned* nx = (const unsigned*)new_xyz + (size_t)q * 3;
    const float qx = __uint_as_float(__hip_atomic_load(nx + 0, __ATOMIC_RELAXED, __HIP_MEMORY_SCOPE_AGENT));
    const float qy = __uint_as_float(__hip_atomic_load(nx + 1, __ATOMIC_RELAXED, __HIP_MEMORY_SCOPE_AGENT));
    const float qz = __uint_as_float(__hip_atomic_load(nx + 2, __ATOMIC_RELAXED, __HIP_MEMORY_SCOPE_AGENT));
    const float qs = __fadd_rn(__fadd_rn(__fmul_rn(qx,qx), __fmul_rn(qy,qy)), __fmul_rn(qz,qz));
    const float* xb = xyz    + (size_t)b * NPTS * 3;
    const float* pb = points + (size_t)b * 13 * NPTS;

    int cnt = 0;
    const unsigned long long lm = (1ull << lane) - 1ull;
    for (int r = 0; r < NPTS / 64; ++r) {
        int n = r * 64 + lane;
        float x = xb[n*3+0], y = xb[n*3+1], z = xb[n*3+2];
        float pn = __fadd_rn(__fadd_rn(__fmul_rn(x,x), __fmul_rn(y,y)), __fmul_rn(z,z));
        float dt = __fadd_rn(__fadd_rn(__fmul_rn(qx,x), __fmul_rn(qy,y)), __fmul_rn(qz,z));
        float sqr = __fsub_rn(__fadd_rn(qs, pn), __fmul_rn(2.0f, dt));
        bool sel = !(sqr > 0.04f);                 // keep iff sqr <= r^2 (f32)
        unsigned long long m = __ballot(sel);
        if (sel) sidx[cnt + __popcll(m & lm)] = (unsigned short)n;
        cnt += (int)__popcll(m);
    }
    const int K = cnt;                             // >= 1
    const int nfirst = (int)sidx[0];

    float mx = -3.0e38f;
    for (int tb = 0; tb < K; tb += 64) {
        int m = tb + lane;
        int n = (m < K) ? (int)sidx[m] : nfirst;   // pad = first neighbor
        float f[16];
        f[0] = xb[n*3+0] - qx;
        f[1] = xb[n*3+1] - qy;
        f[2] = xb[n*3+2] - qz;
#pragma unroll
        for (int c = 0; c < 13; ++c) f[3+c] = pb[c*NPTS + n];
        float h1[32];
#pragma unroll
        for (int o = 0; o < 32; ++o) {
            float acc = b1[o];                     // uniform -> s_load
            const float4* wr = (const float4*)(w1 + o*16);
#pragma unroll
            for (int c4 = 0; c4 < 4; ++c4) {
                float4 wv = wr[c4];
                acc = fmaf(f[c4*4+0], wv.x, acc);
                acc = fmaf(f[c4*4+1], wv.y, acc);
                acc = fmaf(f[c4*4+2], wv.z, acc);
                acc = fmaf(f[c4*4+3], wv.w, acc);
            }
            h1[o] = fmaxf(acc, 0.0f);
        }
        float h2[32];
#pragma unroll
        for (int o = 0; o < 32; ++o) {
            float acc = b2[o];                     // uniform -> s_load
            const float4* wr = (const float4*)(w2 + o*32);
#pragma unroll
            for (int c4 = 0; c4 < 8; ++c4) {
                float4 wv = wr[c4];
                acc = fmaf(h1[c4*4+0], wv.x, acc);
                acc = fmaf(h1[c4*4+1], wv.y, acc);
                acc = fmaf(h1[c4*4+2], wv.z, acc);
                acc = fmaf(h1[c4*4+3], wv.w, acc);
            }
            h2[o] = fmaxf(acc, 0.0f);
        }
        {
            float4* row = (float4*)(sh2 + lane * 36);
#pragma unroll
            for (int c4 = 0; c4 < 8; ++c4)
                row[c4] = make_float4(h2[c4*4+0], h2[c4*4+1], h2[c4*4+2], h2[c4*4+3]);
        }
        int rows = K - tb; if (rows > 64) rows = 64;
#pragma unroll 4
        for (int n2 = 0; n2 < rows; ++n2) {
            const float4* hr = (const float4*)(sh2 + n2 * 36);
            float acc = rb3;
#pragma unroll
            for (int c4 = 0; c4 < 8; ++c4) {
                float4 h = hr[c4];
                acc = fmaf(h.x, wf3[c4*4+0], acc);
                acc = fmaf(h.y, wf3[c4*4+1], acc);
                acc = fmaf(h.z, wf3[c4*4+2], acc);
                acc = fmaf(h.w, wf3[c4*4+3], acc);
            }
            mx = fmaxf(mx, acc);
        }
        // single wave: DS ops in-order -> no barrier between chunks
    }
    new_points[((size_t)b * 64 + lane) * SOUT + s] = mx;   // (B, 64, S)
}

// =================== fused kernel: blocks 0-1 fps, 2-257 group ===============
__global__ __launch_bounds__(TB, 1) void fused_kernel(
        const float* __restrict__ xyz,  const float* __restrict__ points,
        const float* __restrict__ w1,   const float* __restrict__ b1,
        const float* __restrict__ w2,   const float* __restrict__ b2,
        const float* __restrict__ w3,   const float* __restrict__ b3,
        float* __restrict__ new_xyz, float* __restrict__ new_points,
        unsigned* flags, int far0, int far1) {
    __shared__ float4 s_slot[2 * NW];
    __shared__ unsigned short s_sidx[4 * NPTS];
    __shared__ __align__(16) float s_sh2[4 * 64 * 36];
    const int blk = blockIdx.x;
    const int tid = threadIdx.x;
    if (blk < 2) {
        const int bg = blk;
        fps_role<true>(xyz + (size_t)bg * NPTS * 3,
                       new_xyz + (size_t)bg * SOUT * 3,
                       flags + (bg << 6),
                       (bg == 0) ? far0 : far1,
                       s_slot, nullptr, tid);
    } else {
        const int lane = tid & 63;
        const int wvl  = tid >> 6;
        const int q    = (blk - 2) * 4 + wvl;     // 1024 queries
        group_role(xyz, points, w1, b1, w2, b2, w3, b3, new_xyz, new_points,
                   flags, s_sidx + wvl * NPTS, s_sh2 + wvl * 64 * 36, lane, q);
    }
}

// =================== fallback kernels (ws too small): serial path ============
__global__ __launch_bounds__(TB, 1) void fps_kernel(const float* __restrict__ xyz,
                                                    float* __restrict__ new_xyz,
                                                    int far0, int far1) {
    __shared__ float4 s_slot[2 * NW];
    __shared__ __align__(16) float s_scf[SOUT * 3];
    const int bg = blockIdx.x;
    fps_role<false>(xyz + (size_t)bg * NPTS * 3, new_xyz + (size_t)bg * SOUT * 3,
                    nullptr, (bg == 0) ? far0 : far1, s_slot, s_scf, threadIdx.x);
}
__global__ __launch_bounds__(64, 1) void group_kernel(
        const float* __restrict__ xyz,  const float* __restrict__ points,
        const float* __restrict__ w1,   const float* __restrict__ b1,
        const float* __restrict__ w2,   const float* __restrict__ b2,
        const float* __restrict__ w3,   const float* __restrict__ b3,
        const float* __restrict__ new_xyz, float* __restrict__ new_points) {
    __shared__ unsigned short s_sidx[NPTS];
    __shared__ __align__(16) float s_sh2[64 * 36];
    group_role(xyz, points, w1, b1, w2, b2, w3, b3, new_xyz, new_points,
               nullptr, s_sidx, s_sh2, threadIdx.x, blockIdx.x);
}

// ---------------- host: threefry2x32 (JAX key(42) randint seed) --------------
static inline uint32_t rotl32(uint32_t x, int r) { return (x << r) | (x >> (32 - r)); }
static void threefry2x32_host(uint32_t k0, uint32_t k1, uint32_t& x0, uint32_t& x1) {
    const int R[2][4] = {{13,15,26,6},{17,29,16,24}};
    uint32_t ks[3] = {k0, k1, k0 ^ k1 ^ 0x1BD11BDAu};
    x0 += ks[0]; x1 += ks[1];
    for (int i = 0; i < 5; ++i) {
        for (int j = 0; j < 4; ++j) { x0 += x1; x1 = rotl32(x1, R[i & 1][j]); x1 ^= x0; }
        x0 += ks[(i + 1) % 3];
        x1 += ks[(i + 2) % 3] + (uint32_t)(i + 1);
    }
}

extern "C" void kernel_launch(void* const* d_in, const int* in_sizes, int n_in,
                              void* d_out, int out_size, void* d_ws, size_t ws_size,
                              hipStream_t stream) {
    const float* xyz    = (const float*)d_in[0];
    const float* points = (const float*)d_in[1];
    const float* w1 = (const float*)d_in[2];
    const float* b1 = (const float*)d_in[3];
    const float* w2 = (const float*)d_in[4];
    const float* b2 = (const float*)d_in[5];
    const float* w3 = (const float*)d_in[6];
    const float* b3 = (const float*)d_in[7];
    float* out        = (float*)d_out;
    float* new_xyz    = out;                      // (B, S, 3)
    float* new_points = out + NB * SOUT * 3;      // (B, 64, S)

    // jax.random.randint(key(42), (2,), 0, 2048), modern JAX
    // (jax_threefry_partitionable=True): _randint splits the key first:
    //   k1, k2 = split(key); result = random_bits(k2, 32, (2,)) & 2047
    // foldlike split: k2 = threefry((0,42),(0,1)) full pair.
    // partitionable bits: elem i = xor-halves of threefry(k2, (0,i)).
    // (VERIFIED passing in rounds 3-9 — do not change.)
    uint32_t k2a = 0, k2b = 1; threefry2x32_host(0u, 42u, k2a, k2b);
    uint32_t u0 = 0, u1 = 0;  threefry2x32_host(k2a, k2b, u0, u1);
    uint32_t v0 = 0, v1 = 1;  threefry2x32_host(k2a, k2b, v0, v1);
    int far0 = (int)((u0 ^ u1) & (NPTS - 1));
    int far1 = (int)((v0 ^ v1) & (NPTS - 1));

    if (ws_size >= 512) {
        // fused producer-consumer: flags in d_ws (poison 0xAAAAAAAA < FMAGIC
        // -> consumers spin until this launch's publisher writes).
        hipLaunchKernelGGL(fused_kernel, dim3(2 + NB * SOUT / 4), dim3(TB), 0, stream,
                           xyz, points, w1, b1, w2, b2, w3, b3,
                           new_xyz, new_points, (unsigned*)d_ws, far0, far1);
    } else {
        hipLaunchKernelGGL(fps_kernel, dim3(NB), dim3(TB), 0, stream,
                           xyz, new_xyz, far0, far1);
        hipLaunchKernelGGL(group_kernel, dim3(NB * SOUT), dim3(64), 0, stream,
                           xyz, points, w1, b1, w2, b2, w3, b3, new_xyz, new_points);
    }
}

// Round 4
// 343.571 us; speedup vs baseline: 1.5523x; 1.0036x over previous
//
#include <hip/hip_runtime.h>
#include <stdint.h>

#define NPTS 2048
#define SOUT 512
#define NB   2
#define TB   256
#define PPT  8             // fps: points per lane, k-major
#define NW   4             // fps: waves per batch
#define FMAGIC 0xC0DE0000u

typedef float vf2 __attribute__((ext_vector_type(2)));

// ---- DPP wave64 max-reduce (nonneg values; bound_ctrl zero-fill is safe) ----
__device__ __forceinline__ float wave_allmax_f32(float v) {
    int x = __float_as_int(v); int t;
    t = __builtin_amdgcn_update_dpp(x, x, 0x111, 0xF, 0xF, true); v = fmaxf(v, __int_as_float(t)); x = __float_as_int(v);
    t = __builtin_amdgcn_update_dpp(x, x, 0x112, 0xF, 0xF, true); v = fmaxf(v, __int_as_float(t)); x = __float_as_int(v);
    t = __builtin_amdgcn_update_dpp(x, x, 0x114, 0xF, 0xF, true); v = fmaxf(v, __int_as_float(t)); x = __float_as_int(v);
    t = __builtin_amdgcn_update_dpp(x, x, 0x118, 0xF, 0xF, true); v = fmaxf(v, __int_as_float(t)); x = __float_as_int(v);
    t = __builtin_amdgcn_update_dpp(x, x, 0x142, 0xA, 0xF, true); v = fmaxf(v, __int_as_float(t)); x = __float_as_int(v);
    t = __builtin_amdgcn_update_dpp(x, x, 0x143, 0xC, 0xF, true); v = fmaxf(v, __int_as_float(t)); x = __float_as_int(v);
    return __int_as_float(__builtin_amdgcn_readlane(x, 63));
}
__device__ __forceinline__ float4 sel4(bool c, float4 A, float4 B) {
    float4 r;
    r.x = c ? A.x : B.x; r.y = c ? A.y : B.y;
    r.z = c ? A.z : B.z; r.w = c ? A.w : B.w;
    return r;
}

// =================== FPS role (4 waves x 8 pts/lane; hoisted select) =========
// Per round: dist update -> value-only fmax tree (max3-friendly nesting) ->
// coord select vs OWN bv (runs in parallel with the DPP reduce: only the
// winning lane's selection is consumed, and on that lane bv == wmax bitwise,
// since all values are nonneg and fmax returns operands bitwise) -> DPP wave
// reduce -> ballot lowest-lane -> winner writes slot -> barrier -> merge.
// Tie-break = lowest global index n = t*8 + j: lowest slot (descending guarded
// chain, slot 0 applied last), lowest lane (ctz of ballot), lowest wave
// (merge keeps a0 on ties). Distance arithmetic identical to proven version
// (fp contract off, rn each op, fminf chain).
// Publisher (FUSED, wave 3): tri-lane relaxed centroid store each round;
// release flag every 16 rounds BEFORE that round's stores (covers rounds < s;
// the release's wave-wide vmcnt(0) drains all prior lanes' stores).
template<bool FUSED>
__device__ __forceinline__ void fps_role(const float* __restrict__ xb,
                                         float* __restrict__ ob,
                                         unsigned* flagp, int far,
                                         float4* slot /*2*NW*/, float* scf,
                                         int t) {
    const int lane = t & 63;
    const int wvl  = t >> 6;
    __builtin_amdgcn_s_setprio(1);     // producer priority over co-resident pollers
    float v24[24];
    {
        const float4* src = (const float4*)(xb + t * PPT * 3);
#pragma unroll
        for (int j = 0; j < 6; ++j) {
            float4 a = src[j];
            v24[j*4+0] = a.x; v24[j*4+1] = a.y; v24[j*4+2] = a.z; v24[j*4+3] = a.w;
        }
    }
    vf2 PX[4], PY[4], PZ[4], DD[4];
#pragma unroll
    for (int j = 0; j < 4; ++j) {
        PX[j].x = v24[(2*j)*3+0]; PX[j].y = v24[(2*j+1)*3+0];
        PY[j].x = v24[(2*j)*3+1]; PY[j].y = v24[(2*j+1)*3+1];
        PZ[j].x = v24[(2*j)*3+2]; PZ[j].y = v24[(2*j+1)*3+2];
        DD[j].x = 1e10f; DD[j].y = 1e10f;
    }
    float cx = xb[far*3+0], cy = xb[far*3+1], cz = xb[far*3+2];

    for (int s = 0; s < SOUT - 1; ++s) {
        if (FUSED) {
            if (wvl == 3) {
                if (lane == 32 && s >= 16 && (s & 15) == 0)   // covers rounds < s
                    __hip_atomic_store(flagp, FMAGIC + (unsigned)s,
                                       __ATOMIC_RELEASE, __HIP_MEMORY_SCOPE_AGENT);
                if (lane >= 32 && lane < 35) {                // one vmem, 3 lanes
                    float v = (lane == 32) ? cx : ((lane == 33) ? cy : cz);
                    unsigned* o = (unsigned*)ob + s * 3 + (lane - 32);
                    __hip_atomic_store(o, __float_as_uint(v),
                                       __ATOMIC_RELAXED, __HIP_MEMORY_SCOPE_AGENT);
                }
            }
        } else {
            if (t == 0) { scf[s*3+0] = cx; scf[s*3+1] = cy; scf[s*3+2] = cz; }
        }
        {
#pragma clang fp contract(off)
            vf2 vcx; vcx.x = cx; vcx.y = cx;
            vf2 vcy; vcy.x = cy; vcy.y = cy;
            vf2 vcz; vcz.x = cz; vcz.y = cz;
#pragma unroll
            for (int j = 0; j < 4; ++j) {
                vf2 dx = PX[j] - vcx;
                vf2 dy = PY[j] - vcy;
                vf2 dz = PZ[j] - vcz;
                vf2 d2 = (dx*dx + dy*dy) + dz*dz;   // ((xx+yy)+zz), rn each
                DD[j].x = fminf(DD[j].x, d2.x);
                DD[j].y = fminf(DD[j].y, d2.y);
            }
        }
        // --- value-only in-lane reduce (max3-friendly nesting)
        float bv = fmaxf(
            fmaxf(fmaxf(DD[0].x, DD[0].y), fmaxf(DD[1].x, DD[1].y)),
            fmaxf(fmaxf(DD[2].x, DD[2].y), fmaxf(DD[3].x, DD[3].y)));
        // --- coord select vs OWN bv (off critical path; overlaps DPP reduce):
        //     lowest slot j with DD[j]==bv (descending guarded updates, slot 0
        //     last -> lowest index wins). Exact on the winning lane (bv==wmax).
        float bx = PX[3].y, by = PY[3].y, bz = PZ[3].y;            // slot 7
        { bool c = DD[3].x == bv; bx = c?PX[3].x:bx; by = c?PY[3].x:by; bz = c?PZ[3].x:bz; } // 6
        { bool c = DD[2].y == bv; bx = c?PX[2].y:bx; by = c?PY[2].y:by; bz = c?PZ[2].y:bz; } // 5
        { bool c = DD[2].x == bv; bx = c?PX[2].x:bx; by = c?PY[2].x:by; bz = c?PZ[2].x:bz; } // 4
        { bool c = DD[1].y == bv; bx = c?PX[1].y:bx; by = c?PY[1].y:by; bz = c?PZ[1].y:bz; } // 3
        { bool c = DD[1].x == bv; bx = c?PX[1].x:bx; by = c?PY[1].x:by; bz = c?PZ[1].x:bz; } // 2
        { bool c = DD[0].y == bv; bx = c?PX[0].y:bx; by = c?PY[0].y:by; bz = c?PZ[0].y:bz; } // 1
        { bool c = DD[0].x == bv; bx = c?PX[0].x:bx; by = c?PY[0].x:by; bz = c?PZ[0].x:bz; } // 0
        // --- wave reduce + first-occurrence lane
        float wmax = wave_allmax_f32(bv);
        unsigned long long msk = __ballot(bv == wmax);
        int l0 = (int)__builtin_ctzll(msk);
        const int par = s & 1;
        if (lane == l0) slot[par*NW + wvl] = make_float4(wmax, bx, by, bz);
        if (FUSED) {
            // lgkm-only drain (slot handoff) -> publisher vmem stays in flight
            __builtin_amdgcn_s_waitcnt(0xC07F);   // vmcnt(63) exp(7) lgkmcnt(0)
            __builtin_amdgcn_s_barrier();
        } else {
            __syncthreads();
        }
        // depth-2 merge tree; all ties -> lower wave = lower global index
        float4 a0 = slot[par*NW + 0];
        float4 a1 = slot[par*NW + 1];
        float4 a2 = slot[par*NW + 2];
        float4 a3 = slot[par*NW + 3];
        float4 m01 = sel4(a1.x > a0.x, a1, a0);
        float4 m23 = sel4(a3.x > a2.x, a3, a2);
        float4 mf  = sel4(m23.x > m01.x, m23, m01);
        cx = mf.y; cy = mf.z; cz = mf.w;
    }
    // peeled final round: store centroid 511, then final flag
    if (FUSED) {
        if (wvl == 3) {
            if (lane >= 32 && lane < 35) {
                float v = (lane == 32) ? cx : ((lane == 33) ? cy : cz);
                unsigned* o = (unsigned*)ob + (SOUT - 1) * 3 + (lane - 32);
                __hip_atomic_store(o, __float_as_uint(v),
                                   __ATOMIC_RELAXED, __HIP_MEMORY_SCOPE_AGENT);
            }
            if (lane == 32)                    // release: wave-wide vmcnt drain
                __hip_atomic_store(flagp, FMAGIC + 512u,
                                   __ATOMIC_RELEASE, __HIP_MEMORY_SCOPE_AGENT);
        }
    } else {
        if (t == 0) {
            scf[(SOUT-1)*3+0] = cx; scf[(SOUT-1)*3+1] = cy; scf[(SOUT-1)*3+2] = cz;
        }
        __syncthreads();
        for (int i = t; i < SOUT * 3; i += TB) ob[i] = scf[i];
    }
}

// =================== group role (R6/R8 proven body; 1 wave, 1 query) =========
__device__ __forceinline__ void group_role(
        const float* __restrict__ xyz,  const float* __restrict__ points,
        const float* __restrict__ w1,   const float* __restrict__ b1,
        const float* __restrict__ w2,   const float* __restrict__ b2,
        const float* __restrict__ w3,   const float* __restrict__ b3,
        const float* __restrict__ new_xyz, float* __restrict__ new_points,
        const unsigned* flags, unsigned short* sidx, float* sh2,
        int lane, int q) {
    float wf3[32];
    {
        const float4* w3v = (const float4*)(w3 + lane * 32);
#pragma unroll
        for (int j = 0; j < 8; ++j) {
            float4 v = w3v[j];
            wf3[j*4+0] = v.x; wf3[j*4+1] = v.y; wf3[j*4+2] = v.z; wf3[j*4+3] = v.w;
        }
    }
    const float rb3 = b3[lane];
    const int b = q >> 9;
    const int s = q & (SOUT - 1);

    if (flags) {
        const unsigned* flagp = flags + (b << 6);   // 256 B apart
        if (lane == 0) {
            const unsigned tgt = FMAGIC + (unsigned)s + 1u;
            int polls = 0;
            for (;;) {
                unsigned v = __hip_atomic_load(flagp, __ATOMIC_ACQUIRE,
                                               __HIP_MEMORY_SCOPE_AGENT);
                if (v >= tgt && v <= FMAGIC + 512u) break;
                if (++polls > (1 << 18)) break;     // hang insurance
                __builtin_amdgcn_s_sleep(32);
            }
        }
        __threadfence();                            // wave-wide acquire
    }
    const unsigned* nx = (const unsigned*)new_xyz + (size_t)q * 3;
    const float qx = __uint_as_float(__hip_atomic_load(nx + 0, __ATOMIC_RELAXED, __HIP_MEMORY_SCOPE_AGENT));
    const float qy = __uint_as_float(__hip_atomic_load(nx + 1, __ATOMIC_RELAXED, __HIP_MEMORY_SCOPE_AGENT));
    const float qz = __uint_as_float(__hip_atomic_load(nx + 2, __ATOMIC_RELAXED, __HIP_MEMORY_SCOPE_AGENT));
    const float qs = __fadd_rn(__fadd_rn(__fmul_rn(qx,qx), __fmul_rn(qy,qy)), __fmul_rn(qz,qz));
    const float* xb = xyz    + (size_t)b * NPTS * 3;
    const float* pb = points + (size_t)b * 13 * NPTS;

    int cnt = 0;
    const unsigned long long lm = (1ull << lane) - 1ull;
    for (int r = 0; r < NPTS / 64; ++r) {
        int n = r * 64 + lane;
        float x = xb[n*3+0], y = xb[n*3+1], z = xb[n*3+2];
        float pn = __fadd_rn(__fadd_rn(__fmul_rn(x,x), __fmul_rn(y,y)), __fmul_rn(z,z));
        float dt = __fadd_rn(__fadd_rn(__fmul_rn(qx,x), __fmul_rn(qy,y)), __fmul_rn(qz,z));
        float sqr = __fsub_rn(__fadd_rn(qs, pn), __fmul_rn(2.0f, dt));
        bool sel = !(sqr > 0.04f);                 // keep iff sqr <= r^2 (f32)
        unsigned long long m = __ballot(sel);
        if (sel) sidx[cnt + __popcll(m & lm)] = (unsigned short)n;
        cnt += (int)__popcll(m);
    }
    const int K = cnt;                             // >= 1
    const int nfirst = (int)sidx[0];

    float mx = -3.0e38f;
    for (int tb = 0; tb < K; tb += 64) {
        int m = tb + lane;
        int n = (m < K) ? (int)sidx[m] : nfirst;   // pad = first neighbor
        float f[16];
        f[0] = xb[n*3+0] - qx;
        f[1] = xb[n*3+1] - qy;
        f[2] = xb[n*3+2] - qz;
#pragma unroll
        for (int c = 0; c < 13; ++c) f[3+c] = pb[c*NPTS + n];
        float h1[32];
#pragma unroll
        for (int o = 0; o < 32; ++o) {
            float acc = b1[o];                     // uniform -> s_load
            const float4* wr = (const float4*)(w1 + o*16);
#pragma unroll
            for (int c4 = 0; c4 < 4; ++c4) {
                float4 wv = wr[c4];
                acc = fmaf(f[c4*4+0], wv.x, acc);
                acc = fmaf(f[c4*4+1], wv.y, acc);
                acc = fmaf(f[c4*4+2], wv.z, acc);
                acc = fmaf(f[c4*4+3], wv.w, acc);
            }
            h1[o] = fmaxf(acc, 0.0f);
        }
        float h2[32];
#pragma unroll
        for (int o = 0; o < 32; ++o) {
            float acc = b2[o];                     // uniform -> s_load
            const float4* wr = (const float4*)(w2 + o*32);
#pragma unroll
            for (int c4 = 0; c4 < 8; ++c4) {
                float4 wv = wr[c4];
                acc = fmaf(h1[c4*4+0], wv.x, acc);
                acc = fmaf(h1[c4*4+1], wv.y, acc);
                acc = fmaf(h1[c4*4+2], wv.z, acc);
                acc = fmaf(h1[c4*4+3], wv.w, acc);
            }
            h2[o] = fmaxf(acc, 0.0f);
        }
        {
            float4* row = (float4*)(sh2 + lane * 36);
#pragma unroll
            for (int c4 = 0; c4 < 8; ++c4)
                row[c4] = make_float4(h2[c4*4+0], h2[c4*4+1], h2[c4*4+2], h2[c4*4+3]);
        }
        int rows = K - tb; if (rows > 64) rows = 64;
#pragma unroll 4
        for (int n2 = 0; n2 < rows; ++n2) {
            const float4* hr = (const float4*)(sh2 + n2 * 36);
            float acc = rb3;
#pragma unroll
            for (int c4 = 0; c4 < 8; ++c4) {
                float4 h = hr[c4];
                acc = fmaf(h.x, wf3[c4*4+0], acc);
                acc = fmaf(h.y, wf3[c4*4+1], acc);
                acc = fmaf(h.z, wf3[c4*4+2], acc);
                acc = fmaf(h.w, wf3[c4*4+3], acc);
            }
            mx = fmaxf(mx, acc);
        }
        // single wave: DS ops in-order -> no barrier between chunks
    }
    new_points[((size_t)b * 64 + lane) * SOUT + s] = mx;   // (B, 64, S)
}

// =================== fused kernel: blocks 0-1 fps, 2-257 group ===============
__global__ __launch_bounds__(TB, 1) void fused_kernel(
        const float* __restrict__ xyz,  const float* __restrict__ points,
        const float* __restrict__ w1,   const float* __restrict__ b1,
        const float* __restrict__ w2,   const float* __restrict__ b2,
        const float* __restrict__ w3,   const float* __restrict__ b3,
        float* __restrict__ new_xyz, float* __restrict__ new_points,
        unsigned* flags, int far0, int far1) {
    __shared__ float4 s_slot[2 * NW];
    __shared__ unsigned short s_sidx[4 * NPTS];
    __shared__ __align__(16) float s_sh2[4 * 64 * 36];
    const int blk = blockIdx.x;
    const int tid = threadIdx.x;
    if (blk < 2) {
        const int bg = blk;
        fps_role<true>(xyz + (size_t)bg * NPTS * 3,
                       new_xyz + (size_t)bg * SOUT * 3,
                       flags + (bg << 6),
                       (bg == 0) ? far0 : far1,
                       s_slot, nullptr, tid);
    } else {
        const int lane = tid & 63;
        const int wvl  = tid >> 6;
        const int q    = (blk - 2) * 4 + wvl;     // 1024 queries
        group_role(xyz, points, w1, b1, w2, b2, w3, b3, new_xyz, new_points,
                   flags, s_sidx + wvl * NPTS, s_sh2 + wvl * 64 * 36, lane, q);
    }
}

// =================== fallback kernels (ws too small): serial path ============
__global__ __launch_bounds__(TB, 1) void fps_kernel(const float* __restrict__ xyz,
                                                    float* __restrict__ new_xyz,
                                                    int far0, int far1) {
    __shared__ float4 s_slot[2 * NW];
    __shared__ __align__(16) float s_scf[SOUT * 3];
    const int bg = blockIdx.x;
    fps_role<false>(xyz + (size_t)bg * NPTS * 3, new_xyz + (size_t)bg * SOUT * 3,
                    nullptr, (bg == 0) ? far0 : far1, s_slot, s_scf, threadIdx.x);
}
__global__ __launch_bounds__(64, 1) void group_kernel(
        const float* __restrict__ xyz,  const float* __restrict__ points,
        const float* __restrict__ w1,   const float* __restrict__ b1,
        const float* __restrict__ w2,   const float* __restrict__ b2,
        const float* __restrict__ w3,   const float* __restrict__ b3,
        const float* __restrict__ new_xyz, float* __restrict__ new_points) {
    __shared__ unsigned short s_sidx[NPTS];
    __shared__ __align__(16) float s_sh2[64 * 36];
    group_role(xyz, points, w1, b1, w2, b2, w3, b3, new_xyz, new_points,
               nullptr, s_sidx, s_sh2, threadIdx.x, blockIdx.x);
}

// ---------------- host: threefry2x32 (JAX key(42) randint seed) --------------
static inline uint32_t rotl32(uint32_t x, int r) { return (x << r) | (x >> (32 - r)); }
static void threefry2x32_host(uint32_t k0, uint32_t k1, uint32_t& x0, uint32_t& x1) {
    const int R[2][4] = {{13,15,26,6},{17,29,16,24}};
    uint32_t ks[3] = {k0, k1, k0 ^ k1 ^ 0x1BD11BDAu};
    x0 += ks[0]; x1 += ks[1];
    for (int i = 0; i < 5; ++i) {
        for (int j = 0; j < 4; ++j) { x0 += x1; x1 = rotl32(x1, R[i & 1][j]); x1 ^= x0; }
        x0 += ks[(i + 1) % 3];
        x1 += ks[(i + 2) % 3] + (uint32_t)(i + 1);
    }
}

extern "C" void kernel_launch(void* const* d_in, const int* in_sizes, int n_in,
                              void* d_out, int out_size, void* d_ws, size_t ws_size,
                              hipStream_t stream) {
    const float* xyz    = (const float*)d_in[0];
    const float* points = (const float*)d_in[1];
    const float* w1 = (const float*)d_in[2];
    const float* b1 = (const float*)d_in[3];
    const float* w2 = (const float*)d_in[4];
    const float* b2 = (const float*)d_in[5];
    const float* w3 = (const float*)d_in[6];
    const float* b3 = (const float*)d_in[7];
    float* out        = (float*)d_out;
    float* new_xyz    = out;                      // (B, S, 3)
    float* new_points = out + NB * SOUT * 3;      // (B, 64, S)

    // jax.random.randint(key(42), (2,), 0, 2048), modern JAX
    // (jax_threefry_partitionable=True): _randint splits the key first:
    //   k1, k2 = split(key); result = random_bits(k2, 32, (2,)) & 2047
    // foldlike split: k2 = threefry((0,42),(0,1)) full pair.
    // partitionable bits: elem i = xor-halves of threefry(k2, (0,i)).
    // (VERIFIED passing in rounds 3-9 — do not change.)
    uint32_t k2a = 0, k2b = 1; threefry2x32_host(0u, 42u, k2a, k2b);
    uint32_t u0 = 0, u1 = 0;  threefry2x32_host(k2a, k2b, u0, u1);
    uint32_t v0 = 0, v1 = 1;  threefry2x32_host(k2a, k2b, v0, v1);
    int far0 = (int)((u0 ^ u1) & (NPTS - 1));
    int far1 = (int)((v0 ^ v1) & (NPTS - 1));

    if (ws_size >= 512) {
        // fused producer-consumer: flags in d_ws (poison 0xAAAAAAAA < FMAGIC
        // -> consumers spin until this launch's publisher writes).
        hipLaunchKernelGGL(fused_kernel, dim3(2 + NB * SOUT / 4), dim3(TB), 0, stream,
                           xyz, points, w1, b1, w2, b2, w3, b3,
                           new_xyz, new_points, (unsigned*)d_ws, far0, far1);
    } else {
        hipLaunchKernelGGL(fps_kernel, dim3(NB), dim3(TB), 0, stream,
                           xyz, new_xyz, far0, far1);
        hipLaunchKernelGGL(group_kernel, dim3(NB * SOUT), dim3(64), 0, stream,
                           xyz, points, w1, b1, w2, b2, w3, b3, new_xyz, new_points);
    }
}